// Round 13
// baseline (5667.984 us; speedup 1.0000x reference)
//
#include <hip/hip_runtime.h>

// Sizes (fixed by the problem)
#define DZc 512
#define Bc  64
#define Tc  1000
#define DUc 16
#define DXc 256
#define AROW 552           // padded activation row length (bf16 elems)

// Workspace layout:
//   Wp   : bf16 augmented W' [544 k][512 n] B-fragment order  278528 ushort
//   Bp   : bf16 B_obs in B-fragment order                     131072 ushort
//   zs   : bf16 z-history [T][B][DZ]                          32768000 ushort
//   cnts : per-(qpair,half) flag slots, 64-B strided          128 u32

typedef __attribute__((ext_vector_type(4))) float f32x4;
typedef __attribute__((ext_vector_type(8))) short s16x8;
typedef __attribute__((ext_vector_type(4))) unsigned u32x4;

__device__ __forceinline__ unsigned short f2bf(float x) {
  unsigned u = __builtin_bit_cast(unsigned, x);
  u = u + 0x7FFFu + ((u >> 16) & 1u);   // round-to-nearest-even
  return (unsigned short)(u >> 16);
}
__device__ __forceinline__ float bf2f(unsigned short u) {
  unsigned x = ((unsigned)u) << 16;
  return __builtin_bit_cast(float, x);
}
// HW packed f32x2 -> bf16x2 convert (no builtin on gfx950; RNE)
__device__ __forceinline__ unsigned cvt_pk_bf16(float lo, float hi) {
  unsigned r;
  asm("v_cvt_pk_bf16_f32 %0, %1, %2" : "=v"(r) : "v"(lo), "v"(hi));
  return r;
}
// even<->odd lane f32 swap (quad_perm [1,0,3,2])
__device__ __forceinline__ float dpp_swap1(float x) {
  int r = __builtin_amdgcn_mov_dpp(__builtin_bit_cast(int, x), 0xB1, 0xF, 0xF, true);
  return __builtin_bit_cast(float, r);
}

// Pack augmented W' into bf16 MFMA B-fragments.
// W'[n][k]: k<512 -> W[n][k]; k in [512,544) -> Wu[n][k&15].
// Fragment (kt,nt): lane l elem j holds B[k][n], n = nt*16+(l&15),
// k = kt*32+(l>>4)*8+j.  Linear: Wp[((kt*32+nt)*64+l)*8+j]
__global__ void pack_w_kernel(const float* __restrict__ W,
                              const float* __restrict__ Wu,
                              unsigned short* __restrict__ Wp) {
  int d = blockIdx.x * 256 + threadIdx.x;          // 278528 total
  int j = d & 7, l = (d >> 3) & 63, nt = (d >> 9) & 31, kt = d >> 14;
  int n = nt * 16 + (l & 15);
  int k = kt * 32 + ((l >> 4) << 3) + j;
  float val = (k < DZc) ? W[n * DZc + k] : Wu[n * DUc + (k & 15)];
  Wp[d] = f2bf(val);
}

// Pack B_obs[512][256] ([z][x]) into bf16 B-fragments: B[k][n] = B_obs[k][n].
__global__ void pack_b_kernel(const float* __restrict__ B,
                              unsigned short* __restrict__ Bp) {
  int d = blockIdx.x * 256 + threadIdx.x;          // 131072 total
  int j = d & 7, l = (d >> 3) & 63, nt = (d >> 9) & 15, kt = d >> 13;
  int n = nt * 16 + (l & 15);
  int k = kt * 32 + ((l >> 4) << 3) + j;
  Bp[d] = f2bf(B[k * DXc + n]);
}

// Dual-stream recurrence: 4 WGs x 256 threads (4 waves, 1 wave/SIMD).
// WG (q = bid&1, s = bid>>1) runs TWO trial-groups {2q, 2q+1} (16 trials
// each) on n-half s. Per wave: 4 n-tiles x 17 kt = 68 W-frags (272 VGPRs),
// all W in registers. The two independent chains interleave so one group's
// exchange latency (spin / load RT / store drain) hides under the other's
// insert+MFMA phase. Exchange protocol is r6's proven one per group-pair:
// agent-atomic packed z stores into zs, plain fresh-address loads, single
// pair flag published after both groups' stores drain.
__global__ __launch_bounds__(256, 1) void rnn_rec_kernel(
    const float* __restrict__ z0, const float* __restrict__ v,
    const float* __restrict__ h, const float* __restrict__ dp,
    const unsigned short* __restrict__ Wp, unsigned short* __restrict__ zs,
    unsigned int* __restrict__ cnts) {
  __shared__ __align__(16) unsigned short abuf[2][2][16][AROW]; // [grp][par]

  const int bid = blockIdx.x;
  const int q = bid & 1;                           // group-pair id
  const int s = bid >> 1;                          // n-half
  const int tid = threadIdx.x;
  const int lane = tid & 63;
  const int w = tid >> 6;                          // wave 0..3
  const int l15 = lane & 15;
  const int lg = lane >> 4;
  const int b0A = q * 32;                          // group A trials
  const int b0B = q * 32 + 16;                     // group B trials
  const int nbase = s * 256 + w * 64;              // wave's first output

  // ---- one-time: 68 W fragments into regs ----
  s16x8 wr[68];
#pragma unroll
  for (int kt = 0; kt < 17; ++kt) {
#pragma unroll
    for (int ntl = 0; ntl < 4; ++ntl) {
      int nt = s * 16 + w * 4 + ntl;
      wr[kt * 4 + ntl] =
          *(const s16x8*)(Wp + ((size_t)((kt * 32 + nt) * 64 + lane)) * 8);
    }
  }

  // ---- one-time: z0 into accs, h into regs ----
  float hreg[4];
  f32x4 accA[4], accB[4];
#pragma unroll
  for (int ntl = 0; ntl < 4; ++ntl) {
    hreg[ntl] = h[nbase + ntl * 16 + l15];
#pragma unroll
    for (int r = 0; r < 4; ++r) {
      accA[ntl][r] = z0[(size_t)(b0A + lg * 4 + r) * DZc + nbase + ntl * 16 + l15];
      accB[ntl][r] = z0[(size_t)(b0B + lg * 4 + r) * DZc + nbase + ntl * 16 + l15];
    }
  }
  const float decay = expf(-expf(dp[0]));

  // insert slot: thread -> (trial, 16-elem chunk of partner k-half)
  const int trI = tid >> 4;                        // 0..15
  const int k16 = (tid & 15) * 16;                 // 0..240
  const int pk = (1 - s) * 256 + k16;              // partner k base
  float hp[16];
#pragma unroll
  for (int j = 0; j < 16; ++j) hp[j] = h[pk + j];

  // v slots: thread owns (trial, du) for both groups
  const int du = tid & 15, trV = tid >> 4;
  const size_t vbA = ((size_t)(b0A + trV) * DUc + du) * Tc;
  const size_t vbB = ((size_t)(b0B + trV) * DUc + du) * Tc;
  float vA = v[vbA], vB = v[vbB];

  // ---- prologue: a(0) for both groups from z0 (f32) + v(0) ----
#pragma unroll
  for (int grp = 0; grp < 2; ++grp) {
    int b0 = grp ? b0B : b0A;
#pragma unroll
    for (int half = 0; half < 2; ++half) {
      int kk = half * 256 + k16;
      const float* zp = z0 + (size_t)(b0 + trI) * DZc + kk;
      unsigned ow[8];
#pragma unroll
      for (int j2 = 0; j2 < 8; ++j2) {
        float lo = zp[j2 * 2] - h[kk + j2 * 2];
        float hi = zp[j2 * 2 + 1] - h[kk + j2 * 2 + 1];
        lo = lo > 0.f ? lo : 0.f;
        hi = hi > 0.f ? hi : 0.f;
        ow[j2] = cvt_pk_bf16(lo, hi);
      }
      *(u32x4*)&abuf[grp][0][trI][kk] = u32x4{ow[0], ow[1], ow[2], ow[3]};
      *(u32x4*)&abuf[grp][0][trI][kk + 8] = u32x4{ow[4], ow[5], ow[6], ow[7]};
    }
    float vv = grp ? vB : vA;
    unsigned short hi16 = f2bf(vv);
    abuf[grp][0][trV][512 + du] = hi16;
    abuf[grp][0][trV][528 + du] = f2bf(vv - bf2f(hi16));
  }
  asm volatile("s_waitcnt lgkmcnt(0)\n\ts_barrier" ::: "memory");

  // pair flags, 64-B strided: slot (q, s)
  unsigned int* myflag = cnts + (q * 2 + s) * 16;
  const unsigned int* pflag = cnts + (q * 2 + (s ^ 1)) * 16;
  unsigned* zs32 = (unsigned*)zs;                  // zs as packed u32 words

  int p = 0;
  for (int t = 0; t < Tc; ++t) {
    float vnA = v[vbA + (t + 1 < Tc ? t + 1 : Tc - 1)];
    float vnB = v[vbB + (t + 1 < Tc ? t + 1 : Tc - 1)];
#pragma unroll
    for (int ntl = 0; ntl < 4; ++ntl)
#pragma unroll
      for (int r = 0; r < 4; ++r) {
        accA[ntl][r] *= decay;
        accB[ntl][r] *= decay;
      }

    // ---- P1: spin once (pair flag), then issue both partner loads ----
    u32x4 pzA0 = {0,0,0,0}, pzA1 = {0,0,0,0};
    u32x4 pzB0 = {0,0,0,0}, pzB1 = {0,0,0,0};
    if (t > 0) {
      int iters = 0;
      while (__hip_atomic_load(pflag, __ATOMIC_RELAXED,
                               __HIP_MEMORY_SCOPE_AGENT) < (unsigned)t) {
        __builtin_amdgcn_s_sleep(2);
        if (++iters > (1 << 22)) break;            // failsafe: no hangs
      }
      asm volatile("" ::: "memory");               // no hoisting past spin
      const unsigned* srcA =
          zs32 + ((size_t)(t - 1) * Bc + b0A + trI) * 256 + (pk >> 1);
      const unsigned* srcB =
          zs32 + ((size_t)(t - 1) * Bc + b0B + trI) * 256 + (pk >> 1);
      pzA0 = *(const u32x4*)srcA;
      pzA1 = *(const u32x4*)(srcA + 4);
      pzB0 = *(const u32x4*)srcB;
      pzB1 = *(const u32x4*)(srcB + 4);
    }

    // ---- P2: insert A (relu(z-h) + cvt_pk, 16 elems/thread) ----
    if (t > 0) {
      unsigned ow[8];
#pragma unroll
      for (int j2 = 0; j2 < 8; ++j2) {
        unsigned wd = (j2 < 4) ? pzA0[j2] : pzA1[j2 - 4];
        float lo = __builtin_bit_cast(float, wd << 16) - hp[j2 * 2];
        float hi = __builtin_bit_cast(float, wd & 0xFFFF0000u) - hp[j2 * 2 + 1];
        lo = lo > 0.f ? lo : 0.f;
        hi = hi > 0.f ? hi : 0.f;
        ow[j2] = cvt_pk_bf16(lo, hi);
      }
      *(u32x4*)&abuf[0][p][trI][pk] = u32x4{ow[0], ow[1], ow[2], ow[3]};
      *(u32x4*)&abuf[0][p][trI][pk + 8] = u32x4{ow[4], ow[5], ow[6], ow[7]};
    }
    asm volatile("s_waitcnt lgkmcnt(0)\n\ts_barrier" ::: "memory");  // B1

    // ---- P3: MFMA group A (dense 17 kts), then insert B ----
#pragma unroll
    for (int kt = 0; kt < 17; ++kt) {
      s16x8 af = *(const s16x8*)&abuf[0][p][l15][kt * 32 + lg * 8];
#pragma unroll
      for (int ntl = 0; ntl < 4; ++ntl)
        accA[ntl] = __builtin_amdgcn_mfma_f32_16x16x32_bf16(
            af, wr[kt * 4 + ntl], accA[ntl], 0, 0, 0);
    }
    if (t > 0) {
      unsigned ow[8];
#pragma unroll
      for (int j2 = 0; j2 < 8; ++j2) {
        unsigned wd = (j2 < 4) ? pzB0[j2] : pzB1[j2 - 4];
        float lo = __builtin_bit_cast(float, wd << 16) - hp[j2 * 2];
        float hi = __builtin_bit_cast(float, wd & 0xFFFF0000u) - hp[j2 * 2 + 1];
        lo = lo > 0.f ? lo : 0.f;
        hi = hi > 0.f ? hi : 0.f;
        ow[j2] = cvt_pk_bf16(lo, hi);
      }
      *(u32x4*)&abuf[1][p][trI][pk] = u32x4{ow[0], ow[1], ow[2], ow[3]};
      *(u32x4*)&abuf[1][p][trI][pk + 8] = u32x4{ow[4], ow[5], ow[6], ow[7]};
    }
    // z_A stores: issue now, drain during MFMA_B (B2 is lgkm-only)
    const size_t zrowA = (size_t)t * Bc + b0A + lg * 4;
#pragma unroll
    for (int ntl = 0; ntl < 4; ++ntl)
#pragma unroll
      for (int r = 0; r < 4; ++r) {
        float d0 = dpp_swap1(accA[ntl][r]);
        if (!(lane & 1)) {
          unsigned c0 = cvt_pk_bf16(accA[ntl][r], d0);
          __hip_atomic_store(
              zs32 + (zrowA + r) * 256 + (nbase >> 1) + ntl * 8 + (l15 >> 1),
              c0, __ATOMIC_RELAXED, __HIP_MEMORY_SCOPE_AGENT);
        }
      }
    asm volatile("s_waitcnt lgkmcnt(0)\n\ts_barrier" ::: "memory");  // B2

    // ---- P4: MFMA group B (dense 17 kts) ----
#pragma unroll
    for (int kt = 0; kt < 17; ++kt) {
      s16x8 af = *(const s16x8*)&abuf[1][p][l15][kt * 32 + lg * 8];
#pragma unroll
      for (int ntl = 0; ntl < 4; ++ntl)
        accB[ntl] = __builtin_amdgcn_mfma_f32_16x16x32_bf16(
            af, wr[kt * 4 + ntl], accB[ntl], 0, 0, 0);
    }

    // ---- P5: z_B stores, drain, publish pair flag, tails ----
    const size_t zrowB = (size_t)t * Bc + b0B + lg * 4;
#pragma unroll
    for (int ntl = 0; ntl < 4; ++ntl)
#pragma unroll
      for (int r = 0; r < 4; ++r) {
        float d0 = dpp_swap1(accB[ntl][r]);
        if (!(lane & 1)) {
          unsigned c0 = cvt_pk_bf16(accB[ntl][r], d0);
          __hip_atomic_store(
              zs32 + (zrowB + r) * 256 + (nbase >> 1) + ntl * 8 + (l15 >> 1),
              c0, __ATOMIC_RELAXED, __HIP_MEMORY_SCOPE_AGENT);
        }
      }
    asm volatile("s_waitcnt vmcnt(0)" ::: "memory");
    if (tid == 0)
      __hip_atomic_store(myflag, (unsigned)(t + 1), __ATOMIC_RELAXED,
                         __HIP_MEMORY_SCOPE_AGENT);

    // tails: own a(t+1) for both groups -> abuf[g][p^1] + v(t+1) rows
    // (ordered against next step's reads by B1(t+1))
#pragma unroll
    for (int ntl = 0; ntl < 4; ++ntl)
#pragma unroll
      for (int r = 0; r < 4; ++r) {
        float aA = accA[ntl][r] - hreg[ntl]; aA = aA > 0.f ? aA : 0.f;
        float aB = accB[ntl][r] - hreg[ntl]; aB = aB > 0.f ? aB : 0.f;
        float dA = dpp_swap1(aA);
        float dB = dpp_swap1(aB);
        if (!(lane & 1)) {
          *(unsigned*)&abuf[0][p ^ 1][lg * 4 + r][nbase + ntl * 16 + (l15 & ~1)] =
              cvt_pk_bf16(aA, dA);
          *(unsigned*)&abuf[1][p ^ 1][lg * 4 + r][nbase + ntl * 16 + (l15 & ~1)] =
              cvt_pk_bf16(aB, dB);
        }
      }
    {
      unsigned short hiA = f2bf(vnA);
      abuf[0][p ^ 1][trV][512 + du] = hiA;
      abuf[0][p ^ 1][trV][528 + du] = f2bf(vnA - bf2f(hiA));
      unsigned short hiB = f2bf(vnB);
      abuf[1][p ^ 1][trV][512 + du] = hiB;
      abuf[1][p ^ 1][trV][528 + du] = f2bf(vnB - bf2f(hiB));
    }

    p ^= 1;
    vA = vnA;
    vB = vnB;
  }
}

// Projection: x[b][xo][t] = sum_z B_obs[z][xo] * zs[t][b][z] + Bias[xo].
// One WG (256 thr = 4 waves) per (b, 16-t tile); 63 tiles (last masked).
__global__ __launch_bounds__(256, 1) void rnn_proj_kernel(
    const unsigned short* __restrict__ zs, const unsigned short* __restrict__ Bp,
    const float* __restrict__ Bias, float* __restrict__ x) {
  const int wg = blockIdx.x;                       // 64*63 = 4032
  const int b = wg / 63;
  const int tbase = (wg % 63) * 16;
  const int tid = threadIdx.x;
  const int lane = tid & 63;
  const int w = tid >> 6;
  const int l15 = lane & 15, lg = lane >> 4;

  const int trow = tbase + l15;
  const int trc = trow < Tc ? trow : Tc - 1;
  const unsigned short* abase = zs + ((size_t)trc * Bc + b) * DZc + lg * 8;
  const s16x8 zz = {0, 0, 0, 0, 0, 0, 0, 0};

  f32x4 acc[4];
#pragma unroll
  for (int n = 0; n < 4; ++n)
#pragma unroll
    for (int e = 0; e < 4; ++e) acc[n][e] = 0.f;

#pragma unroll
  for (int kt = 0; kt < 16; ++kt) {
    s16x8 af = *(const s16x8*)(abase + kt * 32);
    af = (trow < Tc) ? af : zz;                    // mask pad t-rows
#pragma unroll
    for (int n = 0; n < 4; ++n) {
      s16x8 bf = *(const s16x8*)(Bp + (size_t)((kt * 16 + w * 4 + n) * 64 + lane) * 8);
      acc[n] = __builtin_amdgcn_mfma_f32_16x16x32_bf16(af, bf, acc[n], 0, 0, 0);
    }
  }

  const int t = tbase + lg * 4;                    // regs cover t..t+3
  if (t < Tc) {
#pragma unroll
    for (int n = 0; n < 4; ++n) {
      int xo = (w * 4 + n) * 16 + l15;
      float bias = Bias[xo];
      f32x4 val = acc[n];
#pragma unroll
      for (int e = 0; e < 4; ++e) val[e] += bias;
      *(f32x4*)(x + ((size_t)b * DXc + xo) * Tc + t) = val;
    }
  }
}

extern "C" void kernel_launch(void* const* d_in, const int* in_sizes, int n_in,
                              void* d_out, int out_size, void* d_ws, size_t ws_size,
                              hipStream_t stream) {
  const float* z0   = (const float*)d_in[0];
  const float* v    = (const float*)d_in[1];
  const float* W    = (const float*)d_in[2];
  const float* Wu   = (const float*)d_in[3];
  const float* h    = (const float*)d_in[4];
  const float* dp   = (const float*)d_in[5];
  const float* Bo   = (const float*)d_in[6];
  const float* Bias = (const float*)d_in[7];
  float* x = (float*)d_out;

  unsigned short* Wp = (unsigned short*)d_ws;          // 278528 ushort
  unsigned short* Bp = Wp + 278528;                    // 131072 ushort
  unsigned short* zs = Bp + 131072;                    // 1000*64*512 ushort
  unsigned int* cnts = (unsigned int*)(zs + 32768000); // 128 u32

  hipMemsetAsync(cnts, 0, 128 * sizeof(unsigned int), stream);
  pack_w_kernel<<<1088, 256, 0, stream>>>(W, Wu, Wp);
  pack_b_kernel<<<512, 256, 0, stream>>>(Bo, Bp);
  rnn_rec_kernel<<<4, 256, 0, stream>>>(z0, v, h, dp, Wp, zs, cnts);
  rnn_proj_kernel<<<4032, 256, 0, stream>>>(zs, Bp, Bias, x);
}

// Round 14
// 4242.712 us; speedup vs baseline: 1.3359x; 1.3359x over previous
//
#include <hip/hip_runtime.h>

// Sizes (fixed by the problem)
#define DZc 512
#define Bc  64
#define Tc  1000
#define DUc 16
#define DXc 256
#define AROW 296           // a-buffer row: 256 own-k + 32 v + 8 pad (bf16)

// Workspace layout:
//   Wp   : bf16 augmented W' [544 k][512 n] B-fragment order  278528 ushort
//   Bp   : bf16 B_obs in B-fragment order                     131072 ushort
//   zs   : bf16 z-history [T][B][DZ]                          32768000 ushort
//   cnts : per-(group,half) publish counters, 64-B strided    128 u32
//   pxc  : f32 partial-sum exchange [par][g][slot][16][256]   65536 f32

typedef __attribute__((ext_vector_type(4))) float f32x4;
typedef __attribute__((ext_vector_type(8))) short s16x8;
typedef unsigned long long u64;

__device__ __forceinline__ unsigned short f2bf(float x) {
  unsigned u = __builtin_bit_cast(unsigned, x);
  u = u + 0x7FFFu + ((u >> 16) & 1u);   // round-to-nearest-even
  return (unsigned short)(u >> 16);
}
__device__ __forceinline__ float bf2f(unsigned short u) {
  unsigned x = ((unsigned)u) << 16;
  return __builtin_bit_cast(float, x);
}
// HW packed f32x2 -> bf16x2 convert (no builtin on gfx950; RNE)
__device__ __forceinline__ unsigned cvt_pk_bf16(float lo, float hi) {
  unsigned r;
  asm("v_cvt_pk_bf16_f32 %0, %1, %2" : "=v"(r) : "v"(lo), "v"(hi));
  return r;
}
// even<->odd lane f32 swap (quad_perm [1,0,3,2])
__device__ __forceinline__ float dpp_swap1(float x) {
  int r = __builtin_amdgcn_mov_dpp(__builtin_bit_cast(int, x), 0xB1, 0xF, 0xF, true);
  return __builtin_bit_cast(float, r);
}

// Pack augmented W' into bf16 MFMA B-fragments.
// W'[n][k]: k<512 -> W[n][k]; k in [512,544) -> Wu[n][k&15].
// Fragment (kt,nt): lane l elem j holds B[k][n], n = nt*16+(l&15),
// k = kt*32+(l>>4)*8+j.  Linear: Wp[((kt*32+nt)*64+l)*8+j]
__global__ void pack_w_kernel(const float* __restrict__ W,
                              const float* __restrict__ Wu,
                              unsigned short* __restrict__ Wp) {
  int d = blockIdx.x * 256 + threadIdx.x;          // 278528 total
  int j = d & 7, l = (d >> 3) & 63, nt = (d >> 9) & 31, kt = d >> 14;
  int n = nt * 16 + (l & 15);
  int k = kt * 32 + ((l >> 4) << 3) + j;
  float val = (k < DZc) ? W[n * DZc + k] : Wu[n * DUc + (k & 15)];
  Wp[d] = f2bf(val);
}

// Pack B_obs[512][256] ([z][x]) into bf16 B-fragments: B[k][n] = B_obs[k][n].
__global__ void pack_b_kernel(const float* __restrict__ B,
                              unsigned short* __restrict__ Bp) {
  int d = blockIdx.x * 256 + threadIdx.x;          // 131072 total
  int j = d & 7, l = (d >> 3) & 63, nt = (d >> 9) & 15, kt = d >> 13;
  int n = nt * 16 + (l & 15);
  int k = kt * 32 + ((l >> 4) << 3) + j;
  Bp[d] = f2bf(B[k * DXc + n]);
}

// Recurrence, partial-sum exchange: 8 WGs = 4 trial-groups x 2 halves.
// WG (g,s): 8 waves x 64 (2/SIMD), 16 trials, owns n-half s AND k-half s
// (same indices) -> its a-slice needs NO exchange. Per step:
//  A: partner-n partials over own k (no partner dep) -> store f32 (u64
//     agent atomics) -> drain -> publish (mid-step!)
//  B: own-n MFMAs + v tile, reusing the SAME af registers
//  C: spin (usually resolved), load partner partial, acc += yP,
//     zs plain stores, a(t+1)+v(t+1) tail writes. ONE barrier per step.
__global__ __launch_bounds__(512, 2) void rnn_rec_kernel(
    const float* __restrict__ z0, const float* __restrict__ v,
    const float* __restrict__ h, const float* __restrict__ dp,
    const unsigned short* __restrict__ Wp, unsigned short* __restrict__ zs,
    unsigned int* __restrict__ cnts, u64* __restrict__ pxc) {
  __shared__ __align__(16) unsigned short abuf[2][16][AROW];   // 18.5 KiB
  __shared__ __align__(16) unsigned short wlds[8][2][512];     // 16 KiB

  const int bid = blockIdx.x;
  const int g = bid >> 1;                          // trial group 0..3
  const int s = bid & 1;                           // n/k-half
  const int tid = threadIdx.x;
  const int lane = tid & 63;
  const int w = tid >> 6;                          // wave 0..7
  const int l15 = lane & 15;
  const int lg = lane >> 4;
  const int b0 = g * 16;
  const int nbase = s * 256 + w * 32;              // own-n base (state)
  const int s8 = s * 8;                            // own kt range base

  // ---- one-time: W fragments. Regs: partner-n (A) 16 + own-n (B) 16.
  // v-tile (kt=16, own-n) -> LDS (saves 8 regs). ----
  s16x8 wr[32];
#pragma unroll
  for (int ktl = 0; ktl < 8; ++ktl) {
#pragma unroll
    for (int ntl = 0; ntl < 2; ++ntl) {
      int ktg = s8 + ktl;
      int ntA = (1 - s) * 16 + w * 2 + ntl;
      int ntB = s * 16 + w * 2 + ntl;
      wr[ktl * 2 + ntl] =
          *(const s16x8*)(Wp + ((size_t)((ktg * 32 + ntA) * 64 + lane)) * 8);
      wr[16 + ktl * 2 + ntl] =
          *(const s16x8*)(Wp + ((size_t)((ktg * 32 + ntB) * 64 + lane)) * 8);
    }
  }
#pragma unroll
  for (int ntl = 0; ntl < 2; ++ntl) {
    int ntB = s * 16 + w * 2 + ntl;
    s16x8 f = *(const s16x8*)(Wp + ((size_t)((16 * 32 + ntB) * 64 + lane)) * 8);
    *(s16x8*)&wlds[w][ntl][lane * 8] = f;
  }

  // ---- one-time: z0 into acc, h into regs ----
  float hreg[2];
  f32x4 acc[2];
#pragma unroll
  for (int ntl = 0; ntl < 2; ++ntl) {
    hreg[ntl] = h[nbase + ntl * 16 + l15];
#pragma unroll
    for (int r = 0; r < 4; ++r)
      acc[ntl][r] = z0[(size_t)(b0 + lg * 4 + r) * DZc + nbase + ntl * 16 + l15];
  }
  const float decay = expf(-expf(dp[0]));

  // v staging: threads 0..255 own one (trial, du) slot
  const int du = tid & 15, trV = tid >> 4;
  const size_t vbase = ((size_t)(b0 + trV) * DUc + du) * Tc;
  float vcur = (tid < 256) ? v[vbase] : 0.f;

  // ---- prologue: a(0) own k-half from z0 (f32) + v(0) ----
  {
    const int trI = tid >> 5;                      // 0..15
    const int koff = (tid & 31) * 8;               // 0..248 (buffer k)
    const float* zp = z0 + (size_t)(b0 + trI) * DZc + s * 256 + koff;
    s16x8 ov;
#pragma unroll
    for (int j = 0; j < 8; ++j) {
      float av = zp[j] - h[s * 256 + koff + j];
      ov[j] = (short)f2bf(av > 0.f ? av : 0.f);
    }
    *(s16x8*)&abuf[0][trI][koff] = ov;
  }
  if (tid < 256) {
    unsigned short hi = f2bf(vcur);
    abuf[0][trV][256 + du] = hi;
    abuf[0][trV][272 + du] = f2bf(vcur - bf2f(hi));
  }

  // publish counters, 64-B strided; consumer waits partner cnt >= 8*(t+1)
  unsigned int* mycnt = cnts + (g * 2 + s) * 16;
  const unsigned int* pcnt = cnts + (g * 2 + (s ^ 1)) * 16;
  unsigned* zs32 = (unsigned*)zs;

  // pxc u64 addressing: slot (par, g, who) stride 2048 u64; element
  // offset = (trial)*128 + (w*2+ntl)*8 + (l15>>1)
  const int pxoff = (lg * 4) * 128 + (w * 2) * 8 + (l15 >> 1);

  int p = 0;
  for (int t = 0; t < Tc; ++t) {
    float vnext = (tid < 256) ? v[vbase + (t + 1 < Tc ? t + 1 : Tc - 1)] : 0.f;
#pragma unroll
    for (int ntl = 0; ntl < 2; ++ntl)
#pragma unroll
      for (int r = 0; r < 4; ++r) acc[ntl][r] *= decay;

    // ---- barrier: a(t) writes (tail t-1 / prologue) visible ----
    asm volatile("s_waitcnt lgkmcnt(0)\n\ts_barrier" ::: "memory");

    // ---- phase A: partner-n partials over own k-half ----
    s16x8 af[8];
    f32x4 accP[2];
#pragma unroll
    for (int ntl = 0; ntl < 2; ++ntl)
#pragma unroll
      for (int r = 0; r < 4; ++r) accP[ntl][r] = 0.f;
#pragma unroll
    for (int ktl = 0; ktl < 8; ++ktl) {
      af[ktl] = *(const s16x8*)&abuf[p][l15][ktl * 32 + lg * 8];
      accP[0] = __builtin_amdgcn_mfma_f32_16x16x32_bf16(af[ktl], wr[ktl * 2 + 0], accP[0], 0, 0, 0);
      accP[1] = __builtin_amdgcn_mfma_f32_16x16x32_bf16(af[ktl], wr[ktl * 2 + 1], accP[1], 0, 0, 0);
    }
    // store partials (even-lane u64 agent atomics), drain, publish
    {
      u64* dstp = pxc + (size_t)(((t & 1) * 4 + g) * 2 + s) * 2048 + pxoff;
#pragma unroll
      for (int ntl = 0; ntl < 2; ++ntl)
#pragma unroll
        for (int r = 0; r < 4; ++r) {
          float lo = accP[ntl][r];
          float hi = dpp_swap1(lo);
          if (!(lane & 1)) {
            u64 q = (u64)__builtin_bit_cast(unsigned, lo) |
                    ((u64)__builtin_bit_cast(unsigned, hi) << 32);
            __hip_atomic_store(dstp + r * 128 + ntl * 8, q,
                               __ATOMIC_RELAXED, __HIP_MEMORY_SCOPE_AGENT);
          }
        }
    }
    asm volatile("s_waitcnt vmcnt(0)" ::: "memory");
    if (lane == 0)
      __hip_atomic_fetch_add((unsigned*)mycnt, 1u, __ATOMIC_RELAXED,
                             __HIP_MEMORY_SCOPE_AGENT);

    // ---- phase B: own-n MFMAs (reuse af) + v tile ----
#pragma unroll
    for (int ktl = 0; ktl < 8; ++ktl) {
      acc[0] = __builtin_amdgcn_mfma_f32_16x16x32_bf16(af[ktl], wr[16 + ktl * 2 + 0], acc[0], 0, 0, 0);
      acc[1] = __builtin_amdgcn_mfma_f32_16x16x32_bf16(af[ktl], wr[16 + ktl * 2 + 1], acc[1], 0, 0, 0);
    }
    {
      s16x8 afv = *(const s16x8*)&abuf[p][l15][256 + lg * 8];
      s16x8 bv0 = *(const s16x8*)&wlds[w][0][lane * 8];
      s16x8 bv1 = *(const s16x8*)&wlds[w][1][lane * 8];
      acc[0] = __builtin_amdgcn_mfma_f32_16x16x32_bf16(afv, bv0, acc[0], 0, 0, 0);
      acc[1] = __builtin_amdgcn_mfma_f32_16x16x32_bf16(afv, bv1, acc[1], 0, 0, 0);
    }

    // ---- phase C: spin, load partner partial, acc += yP ----
    {
      int iters = 0;
      while (__hip_atomic_load(pcnt, __ATOMIC_RELAXED,
                               __HIP_MEMORY_SCOPE_AGENT) < (unsigned)(8 * (t + 1))) {
        __builtin_amdgcn_s_sleep(2);
        if (++iters > (1 << 22)) break;            // failsafe: no hangs
      }
      asm volatile("" ::: "memory");               // no hoisting past spin
      const u64* srcp = pxc + (size_t)(((t & 1) * 4 + g) * 2 + (s ^ 1)) * 2048 + pxoff;
      u64 q[2][4];
#pragma unroll
      for (int ntl = 0; ntl < 2; ++ntl)
#pragma unroll
        for (int r = 0; r < 4; ++r)
          if (!(lane & 1))
            q[ntl][r] = __hip_atomic_load(srcp + r * 128 + ntl * 8,
                                          __ATOMIC_RELAXED, __HIP_MEMORY_SCOPE_AGENT);
#pragma unroll
      for (int ntl = 0; ntl < 2; ++ntl)
#pragma unroll
        for (int r = 0; r < 4; ++r) {
          float lo = __builtin_bit_cast(float, (unsigned)q[ntl][r]);
          float hiw = __builtin_bit_cast(float, (unsigned)(q[ntl][r] >> 32));
          float sw = dpp_swap1(hiw);
          acc[ntl][r] += (lane & 1) ? sw : lo;
        }
    }

    // ---- zs[t] plain stores (projection-only data now) ----
    const size_t zrow0 = (size_t)t * Bc + b0 + lg * 4;
#pragma unroll
    for (int r = 0; r < 4; ++r) {
      float d0 = dpp_swap1(acc[0][r]);
      float d1 = dpp_swap1(acc[1][r]);
      if (!(lane & 1)) {
        unsigned* dst = zs32 + (zrow0 + r) * 256 + (nbase >> 1) + (l15 >> 1);
        dst[0] = cvt_pk_bf16(acc[0][r], d0);
        dst[8] = cvt_pk_bf16(acc[1][r], d1);
      }
    }

    // ---- tail: a(t+1) own k-half -> abuf[p^1] + v(t+1) rows ----
#pragma unroll
    for (int r = 0; r < 4; ++r) {
      float a0 = acc[0][r] - hreg[0]; a0 = a0 > 0.f ? a0 : 0.f;
      float a1 = acc[1][r] - hreg[1]; a1 = a1 > 0.f ? a1 : 0.f;
      float d0 = dpp_swap1(a0);
      float d1 = dpp_swap1(a1);
      if (!(lane & 1)) {
        *(unsigned*)&abuf[p ^ 1][lg * 4 + r][w * 32 + (l15 & ~1)] =
            cvt_pk_bf16(a0, d0);
        *(unsigned*)&abuf[p ^ 1][lg * 4 + r][w * 32 + 16 + (l15 & ~1)] =
            cvt_pk_bf16(a1, d1);
      }
    }
    if (tid < 256) {
      unsigned short hi = f2bf(vnext);
      abuf[p ^ 1][trV][256 + du] = hi;
      abuf[p ^ 1][trV][272 + du] = f2bf(vnext - bf2f(hi));
    }

    p ^= 1;
    vcur = vnext;
  }
}

// Projection: x[b][xo][t] = sum_z B_obs[z][xo] * zs[t][b][z] + Bias[xo].
// One WG (256 thr = 4 waves) per (b, 16-t tile); 63 tiles (last masked).
__global__ __launch_bounds__(256, 1) void rnn_proj_kernel(
    const unsigned short* __restrict__ zs, const unsigned short* __restrict__ Bp,
    const float* __restrict__ Bias, float* __restrict__ x) {
  const int wg = blockIdx.x;                       // 64*63 = 4032
  const int b = wg / 63;
  const int tbase = (wg % 63) * 16;
  const int tid = threadIdx.x;
  const int lane = tid & 63;
  const int w = tid >> 6;
  const int l15 = lane & 15, lg = lane >> 4;

  const int trow = tbase + l15;
  const int trc = trow < Tc ? trow : Tc - 1;
  const unsigned short* abase = zs + ((size_t)trc * Bc + b) * DZc + lg * 8;
  const s16x8 zz = {0, 0, 0, 0, 0, 0, 0, 0};

  f32x4 acc[4];
#pragma unroll
  for (int n = 0; n < 4; ++n)
#pragma unroll
    for (int e = 0; e < 4; ++e) acc[n][e] = 0.f;

#pragma unroll
  for (int kt = 0; kt < 16; ++kt) {
    s16x8 af = *(const s16x8*)(abase + kt * 32);
    af = (trow < Tc) ? af : zz;                    // mask pad t-rows
#pragma unroll
    for (int n = 0; n < 4; ++n) {
      s16x8 bf = *(const s16x8*)(Bp + (size_t)((kt * 16 + w * 4 + n) * 64 + lane) * 8);
      acc[n] = __builtin_amdgcn_mfma_f32_16x16x32_bf16(af, bf, acc[n], 0, 0, 0);
    }
  }

  const int t = tbase + lg * 4;                    // regs cover t..t+3
  if (t < Tc) {
#pragma unroll
    for (int n = 0; n < 4; ++n) {
      int xo = (w * 4 + n) * 16 + l15;
      float bias = Bias[xo];
      f32x4 val = acc[n];
#pragma unroll
      for (int e = 0; e < 4; ++e) val[e] += bias;
      *(f32x4*)(x + ((size_t)b * DXc + xo) * Tc + t) = val;
    }
  }
}

extern "C" void kernel_launch(void* const* d_in, const int* in_sizes, int n_in,
                              void* d_out, int out_size, void* d_ws, size_t ws_size,
                              hipStream_t stream) {
  const float* z0   = (const float*)d_in[0];
  const float* v    = (const float*)d_in[1];
  const float* W    = (const float*)d_in[2];
  const float* Wu   = (const float*)d_in[3];
  const float* h    = (const float*)d_in[4];
  const float* dp   = (const float*)d_in[5];
  const float* Bo   = (const float*)d_in[6];
  const float* Bias = (const float*)d_in[7];
  float* x = (float*)d_out;

  unsigned short* Wp = (unsigned short*)d_ws;          // 278528 ushort
  unsigned short* Bp = Wp + 278528;                    // 131072 ushort
  unsigned short* zs = Bp + 131072;                    // 1000*64*512 ushort
  unsigned int* cnts = (unsigned int*)(zs + 32768000); // 128 u32
  u64* pxc = (u64*)(cnts + 128);                       // 32768 u64 (256 KB)

  hipMemsetAsync(cnts, 0, 128 * sizeof(unsigned int), stream);
  pack_w_kernel<<<1088, 256, 0, stream>>>(W, Wu, Wp);
  pack_b_kernel<<<512, 256, 0, stream>>>(Bo, Bp);
  rnn_rec_kernel<<<8, 512, 0, stream>>>(z0, v, h, dp, Wp, zs, cnts, pxc);
  rnn_proj_kernel<<<4032, 256, 0, stream>>>(zs, Bp, Bias, x);
}

// Round 15
// 2050.183 us; speedup vs baseline: 2.7646x; 2.0694x over previous
//
#include <hip/hip_runtime.h>

// Sizes (fixed by the problem)
#define DZc 512
#define Bc  64
#define Tc  1000
#define DUc 16
#define DXc 256
#define AROW 552           // padded activation row length (bf16 elems)

// Workspace layout:
//   Wp   : bf16 augmented W' [544 k][512 n] B-fragment order  278528 ushort
//   Bp   : bf16 B_obs in B-fragment order                     131072 ushort
//   zs   : bf16 z-history [T][B][DZ]                          32768000 ushort
//   cnts : [0..127] pair flags (64-B strided), [128..191] XCD
//          registration table, [192] registration counter      256 u32

typedef __attribute__((ext_vector_type(4))) float f32x4;
typedef __attribute__((ext_vector_type(8))) short s16x8;
typedef __attribute__((ext_vector_type(4))) unsigned u32x4;

__device__ __forceinline__ unsigned short f2bf(float x) {
  unsigned u = __builtin_bit_cast(unsigned, x);
  u = u + 0x7FFFu + ((u >> 16) & 1u);   // round-to-nearest-even
  return (unsigned short)(u >> 16);
}
__device__ __forceinline__ float bf2f(unsigned short u) {
  unsigned x = ((unsigned)u) << 16;
  return __builtin_bit_cast(float, x);
}
// HW packed f32x2 -> bf16x2 convert (no builtin on gfx950; RNE)
__device__ __forceinline__ unsigned cvt_pk_bf16(float lo, float hi) {
  unsigned r;
  asm("v_cvt_pk_bf16_f32 %0, %1, %2" : "=v"(r) : "v"(lo), "v"(hi));
  return r;
}
// even<->odd lane f32 swap (quad_perm [1,0,3,2])
__device__ __forceinline__ float dpp_swap1(float x) {
  int r = __builtin_amdgcn_mov_dpp(__builtin_bit_cast(int, x), 0xB1, 0xF, 0xF, true);
  return __builtin_bit_cast(float, r);
}

// Pack augmented W' into bf16 MFMA B-fragments.
// W'[n][k]: k<512 -> W[n][k]; k in [512,544) -> Wu[n][k&15].
// Fragment (kt,nt): lane l elem j holds B[k][n], n = nt*16+(l&15),
// k = kt*32+(l>>4)*8+j.  Linear: Wp[((kt*32+nt)*64+l)*8+j]
__global__ void pack_w_kernel(const float* __restrict__ W,
                              const float* __restrict__ Wu,
                              unsigned short* __restrict__ Wp) {
  int d = blockIdx.x * 256 + threadIdx.x;          // 278528 total
  int j = d & 7, l = (d >> 3) & 63, nt = (d >> 9) & 31, kt = d >> 14;
  int n = nt * 16 + (l & 15);
  int k = kt * 32 + ((l >> 4) << 3) + j;
  float val = (k < DZc) ? W[n * DZc + k] : Wu[n * DUc + (k & 15)];
  Wp[d] = f2bf(val);
}

// Pack B_obs[512][256] ([z][x]) into bf16 B-fragments: B[k][n] = B_obs[k][n].
__global__ void pack_b_kernel(const float* __restrict__ B,
                              unsigned short* __restrict__ Bp) {
  int d = blockIdx.x * 256 + threadIdx.x;          // 131072 total
  int j = d & 7, l = (d >> 3) & 63, nt = (d >> 9) & 15, kt = d >> 13;
  int n = nt * 16 + (l & 15);
  int k = kt * 32 + ((l >> 4) << 3) + j;
  Bp[d] = f2bf(B[k * DXc + n]);
}

// Recurrence, N-split pairs with RUNTIME XCD PAIRING ELECTION.
// 64 blocks launch; each registers its XCC_ID; all blocks deterministically
// compute the same pairing from the full table: first 4 XCDs with >=2
// registrants give 4 same-XCD pairs (fast: plain stores through the SHARED
// per-XCD L2), shortfall falls back to agent atomics (r12 slow path).
// Surplus blocks exit. Active pair body == r12 (8 waves, 16 trials,
// 34 W-frags/wave in regs, 2 barriers/step, early publish).
__global__ __launch_bounds__(512, 2) void rnn_rec_kernel(
    const float* __restrict__ z0, const float* __restrict__ v,
    const float* __restrict__ h, const float* __restrict__ dp,
    const unsigned short* __restrict__ Wp, unsigned short* __restrict__ zs,
    unsigned int* __restrict__ cnts) {
  __shared__ __align__(16) unsigned short abuf[2][16][AROW];   // 34.5 KiB
  __shared__ unsigned role_sh;

  const int bid = blockIdx.x;
  const int tid = threadIdx.x;

  unsigned int* regtab = cnts + 128;               // 64 slots
  unsigned int* regcnt = cnts + 192;

  // ---- pairing election ----
  if (tid == 0) {
    unsigned x;
    asm volatile("s_getreg_b32 %0, hwreg(HW_REG_XCC_ID)" : "=s"(x));
    x &= 0xFu;
    __hip_atomic_store(&regtab[bid], x | 0x100u, __ATOMIC_RELAXED,
                       __HIP_MEMORY_SCOPE_AGENT);
    __hip_atomic_fetch_add(regcnt, 1u, __ATOMIC_RELAXED,
                           __HIP_MEMORY_SCOPE_AGENT);
    int it = 0;
    while (__hip_atomic_load(regcnt, __ATOMIC_RELAXED,
                             __HIP_MEMORY_SCOPE_AGENT) < 64u &&
           ++it < (1 << 24))
      __builtin_amdgcn_s_sleep(1);
    unsigned tab[64];
    for (int i = 0; i < 64; ++i)
      tab[i] = __hip_atomic_load(&regtab[i], __ATOMIC_RELAXED,
                                 __HIP_MEMORY_SCOPE_AGENT);
    unsigned used[64];
    for (int i = 0; i < 64; ++i) used[i] = 0;
    int pg = -1, ps = -1, fm = 0, pairs = 0;
    // same-XCD pairs first
    for (int xc = 0; xc < 16 && pairs < 4; ++xc) {
      int first = -1;
      for (int i = 0; i < 64 && pairs < 4; ++i) {
        if (!(tab[i] & 0x100u) || used[i] || (int)(tab[i] & 0xFu) != xc)
          continue;
        if (first < 0) { first = i; }
        else {
          if (bid == first) { pg = pairs; ps = 0; fm = 1; }
          if (bid == i)     { pg = pairs; ps = 1; fm = 1; }
          used[first] = used[i] = 1;
          ++pairs;
          first = -1;
        }
      }
    }
    // fallback pairs (cross-XCD, slow mode)
    while (pairs < 4) {
      int a = -1, b = -1;
      for (int i = 0; i < 64; ++i) {
        if (used[i] || !(tab[i] & 0x100u)) continue;
        if (a < 0) a = i;
        else { b = i; break; }
      }
      if (a < 0) a = pairs * 2;
      if (b < 0) b = pairs * 2 + 1;                // timeout-only static fill
      if (bid == a) { pg = pairs; ps = 0; fm = 0; }
      if (bid == b) { pg = pairs; ps = 1; fm = 0; }
      if (a < 64) used[a] = 1;
      if (b < 64) used[b] = 1;
      ++pairs;
    }
    role_sh = (pg < 0) ? 0xFFFFFFFFu
              : ((unsigned)pg | ((unsigned)ps << 8) | ((unsigned)fm << 16));
  }
  __syncthreads();
  const unsigned role = role_sh;
  if (role == 0xFFFFFFFFu) return;                 // surplus block
  const int g = role & 0xFF;
  const int s = (role >> 8) & 0xFF;
  const bool fast = ((role >> 16) & 1) != 0;

  const int lane = tid & 63;
  const int w = tid >> 6;                          // wave 0..7
  const int l15 = lane & 15;
  const int lg = lane >> 4;
  const int b0 = g * 16;
  const int nbase = s * 256 + w * 32;              // wave's first output

  // flag slots, 64-B strided
  unsigned int* mycnt = cnts + (g * 2 + s) * 16;
  const unsigned int* pcnt = cnts + (g * 2 + (s ^ 1)) * 16;

  // ---- one-time: 34 W fragments into regs, straight kt ordering ----
  s16x8 wr[34];
#pragma unroll
  for (int kt = 0; kt < 17; ++kt) {
#pragma unroll
    for (int ntl = 0; ntl < 2; ++ntl) {
      int nt = s * 16 + w * 2 + ntl;
      wr[kt * 2 + ntl] =
          *(const s16x8*)(Wp + ((size_t)((kt * 32 + nt) * 64 + lane)) * 8);
    }
  }

  // ---- one-time: z0 into acc, h into regs ----
  float hreg[2];
  f32x4 acc[2];
#pragma unroll
  for (int ntl = 0; ntl < 2; ++ntl) {
    hreg[ntl] = h[nbase + ntl * 16 + l15];
#pragma unroll
    for (int r = 0; r < 4; ++r)
      acc[ntl][r] = z0[(size_t)(b0 + lg * 4 + r) * DZc + nbase + ntl * 16 + l15];
  }
  const float decay = expf(-expf(dp[0]));

  // partner-insert slot: thread -> (trial, 8-k chunk of partner half)
  const int ptrial = tid >> 5;                     // 0..15
  const int koff = (tid & 31) * 8;                 // 0..248
  const int pk = (1 - s) * 256 + koff;             // partner k base
  float hpart[8];
#pragma unroll
  for (int j = 0; j < 8; ++j) hpart[j] = h[pk + j];

  // v staging: threads 0..255 own one (trial, du) slot
  const int du = tid & 15, trr = tid >> 4;
  const size_t vbase = ((size_t)(b0 + trr) * DUc + du) * Tc;
  float vcur = (tid < 256) ? v[vbase] : 0.f;

  // ---- prologue: build FULL a(0) from z0 (f32) + v(0) ----
#pragma unroll
  for (int half = 0; half < 2; ++half) {
    int kk = half * 256 + koff;
    const float* zp = z0 + (size_t)(b0 + ptrial) * DZc + kk;
    s16x8 ov;
#pragma unroll
    for (int j = 0; j < 8; ++j) {
      float av = zp[j] - h[kk + j];
      ov[j] = (short)f2bf(av > 0.f ? av : 0.f);
    }
    *(s16x8*)&abuf[0][ptrial][kk] = ov;
  }
  if (tid < 256) {
    unsigned short hi = f2bf(vcur);
    abuf[0][trr][512 + du] = hi;
    abuf[0][trr][528 + du] = f2bf(vcur - bf2f(hi));
  }
  asm volatile("s_waitcnt lgkmcnt(0)\n\ts_barrier" ::: "memory");

  unsigned* zs32 = (unsigned*)zs;                  // zs as packed u32 words

  int p = 0;
  for (int t = 0; t < Tc; ++t) {
    // early-issue next v; decay acc (independent of partner)
    float vnext = (tid < 256) ? v[vbase + (t + 1 < Tc ? t + 1 : Tc - 1)] : 0.f;
#pragma unroll
    for (int ntl = 0; ntl < 2; ++ntl)
#pragma unroll
      for (int r = 0; r < 4; ++r) acc[ntl][r] *= decay;

    // ---- phase 1: spin for partner z(t), load, insert into abuf[p] ----
    if (t > 0) {
      int iters = 0;
      while (__hip_atomic_load(pcnt, __ATOMIC_RELAXED,
                               __HIP_MEMORY_SCOPE_AGENT) < (unsigned)t) {
        __builtin_amdgcn_s_sleep(2);
        if (++iters > (1 << 22)) break;            // failsafe: no hangs
      }
      asm volatile("" ::: "memory");               // no hoisting past spin
      u32x4 pz4 = *(const u32x4*)(zs32 +
            ((size_t)(t - 1) * Bc + b0 + ptrial) * 256 + (pk >> 1));
      u32x4 av;
#pragma unroll
      for (int j2 = 0; j2 < 4; ++j2) {
        unsigned wd = pz4[j2];
        float lo = __builtin_bit_cast(float, wd << 16);
        float hi = __builtin_bit_cast(float, wd & 0xFFFF0000u);
        lo = lo - hpart[j2 * 2];
        hi = hi - hpart[j2 * 2 + 1];
        lo = lo > 0.f ? lo : 0.f;
        hi = hi > 0.f ? hi : 0.f;
        av[j2] = cvt_pk_bf16(lo, hi);
      }
      *(u32x4*)&abuf[p][ptrial][pk] = av;
    }

    // ---- barrier alpha: inserts (this step) + a/v tail writes (previous
    // step) visible to all waves before the MFMA reads ----
    asm volatile("s_waitcnt lgkmcnt(0)\n\ts_barrier" ::: "memory");

    // ---- dense MFMA block: all 17 kts ----
#pragma unroll
    for (int kt = 0; kt < 17; ++kt) {
      s16x8 af = *(const s16x8*)&abuf[p][l15][kt * 32 + lg * 8];
      acc[0] = __builtin_amdgcn_mfma_f32_16x16x32_bf16(af, wr[kt * 2 + 0], acc[0], 0, 0, 0);
      acc[1] = __builtin_amdgcn_mfma_f32_16x16x32_bf16(af, wr[kt * 2 + 1], acc[1], 0, 0, 0);
    }

    // ---- z(t+1) -> zs[t]: plain stores (same-XCD L2) or agent atomics ----
    const size_t zrow0 = (size_t)t * Bc + b0 + lg * 4;
#pragma unroll
    for (int r = 0; r < 4; ++r) {
      float d0 = dpp_swap1(acc[0][r]);
      float d1 = dpp_swap1(acc[1][r]);
      if (!(lane & 1)) {
        unsigned c0 = cvt_pk_bf16(acc[0][r], d0);
        unsigned c1 = cvt_pk_bf16(acc[1][r], d1);
        unsigned* dst = zs32 + (zrow0 + r) * 256 + (nbase >> 1) + (l15 >> 1);
        if (fast) {
          dst[0] = c0;
          dst[8] = c1;
        } else {
          __hip_atomic_store(dst, c0, __ATOMIC_RELAXED, __HIP_MEMORY_SCOPE_AGENT);
          __hip_atomic_store(dst + 8, c1, __ATOMIC_RELAXED, __HIP_MEMORY_SCOPE_AGENT);
        }
      }
    }

    // ---- barrier beta: all waves' z stores drained; publish EARLY ----
    asm volatile("s_waitcnt vmcnt(0)" ::: "memory");
    __builtin_amdgcn_s_barrier();
    if (tid == 0)
      __hip_atomic_store(mycnt, (unsigned)(t + 1), __ATOMIC_RELAXED,
                         __HIP_MEMORY_SCOPE_AGENT);

    // ---- tail: own a(t+1) -> abuf[p^1] + v(t+1) rows (ordered by next
    // step's barrier alpha) ----
#pragma unroll
    for (int r = 0; r < 4; ++r) {
      float a0 = acc[0][r] - hreg[0]; a0 = a0 > 0.f ? a0 : 0.f;
      float a1 = acc[1][r] - hreg[1]; a1 = a1 > 0.f ? a1 : 0.f;
      float d0 = dpp_swap1(a0);
      float d1 = dpp_swap1(a1);
      if (!(lane & 1)) {
        unsigned c0 = cvt_pk_bf16(a0, d0);
        unsigned c1 = cvt_pk_bf16(a1, d1);
        *(unsigned*)&abuf[p ^ 1][lg * 4 + r][nbase + (l15 & ~1)] = c0;
        *(unsigned*)&abuf[p ^ 1][lg * 4 + r][nbase + 16 + (l15 & ~1)] = c1;
      }
    }
    if (tid < 256) {
      unsigned short hi = f2bf(vnext);
      abuf[p ^ 1][trr][512 + du] = hi;
      abuf[p ^ 1][trr][528 + du] = f2bf(vnext - bf2f(hi));
    }

    p ^= 1;
    vcur = vnext;
  }
}

// Projection: x[b][xo][t] = sum_z B_obs[z][xo] * zs[t][b][z] + Bias[xo].
// One WG (256 thr = 4 waves) per (b, 16-t tile); 63 tiles (last masked).
__global__ __launch_bounds__(256, 1) void rnn_proj_kernel(
    const unsigned short* __restrict__ zs, const unsigned short* __restrict__ Bp,
    const float* __restrict__ Bias, float* __restrict__ x) {
  const int wg = blockIdx.x;                       // 64*63 = 4032
  const int b = wg / 63;
  const int tbase = (wg % 63) * 16;
  const int tid = threadIdx.x;
  const int lane = tid & 63;
  const int w = tid >> 6;
  const int l15 = lane & 15, lg = lane >> 4;

  const int trow = tbase + l15;
  const int trc = trow < Tc ? trow : Tc - 1;
  const unsigned short* abase = zs + ((size_t)trc * Bc + b) * DZc + lg * 8;
  const s16x8 zz = {0, 0, 0, 0, 0, 0, 0, 0};

  f32x4 acc[4];
#pragma unroll
  for (int n = 0; n < 4; ++n)
#pragma unroll
    for (int e = 0; e < 4; ++e) acc[n][e] = 0.f;

#pragma unroll
  for (int kt = 0; kt < 16; ++kt) {
    s16x8 af = *(const s16x8*)(abase + kt * 32);
    af = (trow < Tc) ? af : zz;                    // mask pad t-rows
#pragma unroll
    for (int n = 0; n < 4; ++n) {
      s16x8 bf = *(const s16x8*)(Bp + (size_t)((kt * 16 + w * 4 + n) * 64 + lane) * 8);
      acc[n] = __builtin_amdgcn_mfma_f32_16x16x32_bf16(af, bf, acc[n], 0, 0, 0);
    }
  }

  const int t = tbase + lg * 4;                    // regs cover t..t+3
  if (t < Tc) {
#pragma unroll
    for (int n = 0; n < 4; ++n) {
      int xo = (w * 4 + n) * 16 + l15;
      float bias = Bias[xo];
      f32x4 val = acc[n];
#pragma unroll
      for (int e = 0; e < 4; ++e) val[e] += bias;
      *(f32x4*)(x + ((size_t)b * DXc + xo) * Tc + t) = val;
    }
  }
}

extern "C" void kernel_launch(void* const* d_in, const int* in_sizes, int n_in,
                              void* d_out, int out_size, void* d_ws, size_t ws_size,
                              hipStream_t stream) {
  const float* z0   = (const float*)d_in[0];
  const float* v    = (const float*)d_in[1];
  const float* W    = (const float*)d_in[2];
  const float* Wu   = (const float*)d_in[3];
  const float* h    = (const float*)d_in[4];
  const float* dp   = (const float*)d_in[5];
  const float* Bo   = (const float*)d_in[6];
  const float* Bias = (const float*)d_in[7];
  float* x = (float*)d_out;

  unsigned short* Wp = (unsigned short*)d_ws;          // 278528 ushort
  unsigned short* Bp = Wp + 278528;                    // 131072 ushort
  unsigned short* zs = Bp + 131072;                    // 1000*64*512 ushort
  unsigned int* cnts = (unsigned int*)(zs + 32768000); // 256 u32

  hipMemsetAsync(cnts, 0, 256 * sizeof(unsigned int), stream);
  pack_w_kernel<<<1088, 256, 0, stream>>>(W, Wu, Wp);
  pack_b_kernel<<<512, 256, 0, stream>>>(Bo, Bp);
  rnn_rec_kernel<<<64, 512, 0, stream>>>(z0, v, h, dp, Wp, zs, cnts);
  rnn_proj_kernel<<<4032, 256, 0, stream>>>(zs, Bp, Bias, x);
}